// Round 4
// baseline (658.370 us; speedup 1.0000x reference)
//
#include <hip/hip_runtime.h>
#include <hip/hip_bf16.h>

// dims
constexpr int BB = 16, IC = 512, OC = 512, HH = 64, WW = 64, HW = 64 * 64, SD = 512;
constexpr float MOD_SCALE = 0.04419417382415922f;      // 1/sqrt(512)
constexpr float CONV_SCALE = 0.014731391274719739f;    // 1/sqrt(512*9)
constexpr float CONV_SCALE2 = 2.170138888888889e-4f;   // 1/4608

typedef float f32x4 __attribute__((ext_vector_type(4)));
typedef short bf16x8 __attribute__((ext_vector_type(8)));

#define VMWAIT(n) asm volatile("s_waitcnt vmcnt(" #n ")" ::: "memory")

__device__ __forceinline__ unsigned short f2bf(float x) {
  __hip_bfloat16 h = __float2bfloat16(x);
  return *(unsigned short*)&h;
}

// ---------------- kernel 1: s[b][ic] = style @ (mod_weight*ms)^T + mod_bias ----
__global__ void k_style(const float* __restrict__ style, const float* __restrict__ mw,
                        const float* __restrict__ mb, float* __restrict__ s) {
  __shared__ float st[SD];
  const int b = blockIdx.x;
  for (int i = threadIdx.x; i < SD; i += 256) st[i] = style[b * SD + i];
  __syncthreads();
  for (int ic = threadIdx.x; ic < IC; ic += 256) {
    const float4* wr = (const float4*)(mw + (size_t)ic * SD);
    float acc = 0.f;
    for (int d = 0; d < SD / 4; ++d) {
      float4 w4 = wr[d];
      float4 s4 = *(const float4*)&st[d * 4];
      acc += w4.x * s4.x + w4.y * s4.y + w4.z * s4.z + w4.w * s4.w;
    }
    s[b * IC + ic] = acc * MOD_SCALE + mb[ic];
  }
}

// ---------------- kernel 2: pack weights [tap][oc][ic] bf16 + w2sum[oc][ic] ----
__global__ void k_pack(const float* __restrict__ w, unsigned short* __restrict__ wpack,
                       float* __restrict__ w2sum) {
  const int oc = blockIdx.x;
  const int ic0 = threadIdx.x * 2;
  const float* p = w + (size_t)oc * IC * 9 + (size_t)ic0 * 9;
  float v[18];
#pragma unroll
  for (int i = 0; i < 18; ++i) v[i] = p[i];
  float s0 = 0.f, s1 = 0.f;
#pragma unroll
  for (int t = 0; t < 9; ++t) { s0 += v[t] * v[t]; s1 += v[9 + t] * v[9 + t]; }
  *(float2*)&w2sum[oc * IC + ic0] = make_float2(s0, s1);
#pragma unroll
  for (int t = 0; t < 9; ++t) {
    unsigned int pk = (unsigned int)f2bf(v[t]) | ((unsigned int)f2bf(v[9 + t]) << 16);
    *(unsigned int*)&wpack[((size_t)t * OC + oc) * IC + ic0] = pk;
  }
}

// ---------------- kernel 3: fscale[b][oc] = conv_scale * rsqrt(cs2*sum + eps) --
__global__ void k_demod(const float* __restrict__ s, const float* __restrict__ w2sum,
                        float* __restrict__ fscale) {
  __shared__ float s2[IC];
  const int b = blockIdx.x;
  for (int i = threadIdx.x; i < IC; i += 256) { float v = s[b * IC + i]; s2[i] = v * v; }
  __syncthreads();
  for (int oc = threadIdx.x; oc < OC; oc += 256) {
    const float4* wr = (const float4*)(w2sum + (size_t)oc * IC);
    float acc = 0.f;
    for (int i4 = 0; i4 < IC / 4; ++i4) {
      float4 w4 = wr[i4];
      float4 q4 = *(const float4*)&s2[i4 * 4];
      acc += w4.x * q4.x + w4.y * q4.y + w4.z * q4.z + w4.w * q4.w;
    }
    fscale[b * OC + oc] = CONV_SCALE * rsqrtf(CONV_SCALE2 * acc + 1e-8f);
  }
}

// ---------------- kernel 4: the conv (implicit GEMM, bf16 MFMA) ----------------
// grid: 2048 = 16 b * 4 mblk * 32 nblk; block 256 = 4 waves.
// Wave tiling: 4x1 strips — wave w owns oc rows [32w,32w+32) x all 128 px.
// A (weights) is WAVE-PRIVATE: wave w DMAs and reads only its own 32 A-rows
// -> no barrier per tap. 4 rotating A-buffers, 3-deep DMA prefetch, counted
// vmcnt only (4 steady / 20 while stageB loads in flight). Barriers: 2 per icb
// around the shared-B restage, with T14 split (x loads issued at tap 5, hidden
// under taps 5-8 compute; ds_writes after the barrier).
__global__ __launch_bounds__(256, 3) void k_conv(
    const float* __restrict__ x, const unsigned short* __restrict__ wpack,
    const float* __restrict__ s, const float* __restrict__ fscale,
    float* __restrict__ out) {
  __shared__ __align__(128) unsigned short Asm[4][128 * 32];  // 4 bufs, [oc][ic] swizzled
  __shared__ __align__(128) unsigned short Bsm[264 * 32];     // [h''*66 + w''][ic] swizzled

  const int bx = blockIdx.x;
  const int b = bx >> 7, mblk = (bx >> 5) & 3, nblk = bx & 31;
  const int tid = threadIdx.x;
  const int wave = tid >> 6, lane = tid & 63;
  const int lrow = lane & 15, lk = lane >> 4;
  const int h0 = nblk * 2;  // 2 output rows; halo rows h0-1 .. h0+2
  const float* xb = x + (size_t)b * IC * HW;
  const float* sb = s + b * IC;

  f32x4 acc[2][8];
#pragma unroll
  for (int i = 0; i < 2; ++i)
#pragma unroll
    for (int j = 0; j < 8; ++j) acc[i][j] = f32x4{0.f, 0.f, 0.f, 0.f};

  // zero the w-halo rows (w''==0 and w''==65 for the 4 h rows), once
  {
    int q = tid >> 5;  // 0..7
    int hh = q >> 1, wz = (q & 1) ? 65 : 0;
    Bsm[(hh * 66 + wz) * 32 + (tid & 31)] = 0;
  }

  // per-wave B staging coords: wave -> halo row, lane -> w
  const int sh = h0 - 1 + wave;
  const bool vh = (sh >= 0) && (sh < HH);
  const int shs = vh ? sh : 0;
  const int brow = wave * 66 + lane + 1;
  const int bswz = (brow >> 1) & 3;

  float xv[32];  // T14 staging regs: raw x values, loaded early, written late
  auto ld_x = [&](int icb) {
    const float* src = xb + (size_t)(icb * 32) * HW + shs * WW + lane;
#pragma unroll
    for (int k = 0; k < 32; ++k) xv[k] = src[(size_t)k * HW];
  };
  auto wr_B = [&](int icb) {
#pragma unroll
    for (int c = 0; c < 4; ++c) {
      unsigned int pk[4];
#pragma unroll
      for (int jj = 0; jj < 4; ++jj) {
        int k = c * 8 + jj * 2;
        float m0 = vh ? sb[icb * 32 + k] : 0.f;
        float m1 = vh ? sb[icb * 32 + k + 1] : 0.f;
        pk[jj] = (unsigned int)f2bf(xv[k] * m0) | ((unsigned int)f2bf(xv[k + 1] * m1) << 16);
      }
      *(uint4*)&Bsm[brow * 32 + ((c ^ bswz) * 8)] = make_uint4(pk[0], pk[1], pk[2], pk[3]);
    }
  };
  // wave-private A DMA: wave w writes rows [32w,32w+32) (2 vmem ops per call)
  auto issueA = [&](int tap, int icb, int nb) {
    const unsigned short* base =
        wpack + ((size_t)(tap * OC + mblk * 128)) * IC + icb * 32;
#pragma unroll
    for (int q = 0; q < 2; ++q) {
      int r = wave * 32 + q * 16 + (lane >> 2);
      int cs = (lane & 3) ^ ((r >> 1) & 3);
      const unsigned short* g = base + (size_t)r * IC + cs * 8;
      unsigned short* l = &Asm[nb][(wave * 32 + q * 16) * 32];
      __builtin_amdgcn_global_load_lds(
          (const __attribute__((address_space(1))) void*)g,
          (__attribute__((address_space(3))) void*)l, 16, 0, 0);
    }
  };

  auto do_tap = [&](int t, int bufr) {
    bf16x8 af[2], bfr[8];
#pragma unroll
    for (int i = 0; i < 2; ++i) {
      int r = wave * 32 + i * 16 + lrow;  // own rows only
      af[i] = *(const bf16x8*)&Asm[bufr][r * 32 + ((lk ^ ((r >> 1) & 3)) * 8)];
    }
    const int dh = t / 3 - 1, dw = t % 3 - 1;
#pragma unroll
    for (int j = 0; j < 8; ++j) {
      int r = ((j >> 2) + dh + 1) * 66 + (j & 3) * 16 + lrow + dw + 1;
      bfr[j] = *(const bf16x8*)&Bsm[r * 32 + ((lk ^ ((r >> 1) & 3)) * 8)];
    }
    __builtin_amdgcn_s_setprio(1);
#pragma unroll
    for (int i = 0; i < 2; ++i)
#pragma unroll
      for (int j = 0; j < 8; ++j)
        acc[i][j] =
            __builtin_amdgcn_mfma_f32_16x16x32_bf16(af[i], bfr[j], acc[i][j], 0, 0, 0);
    __builtin_amdgcn_s_setprio(0);
  };

  // ---- prologue: B(0) staged, A taps 0..2 in flight ----
  ld_x(0);
  issueA(0, 0, 0);
  issueA(1, 0, 1);
  issueA(2, 0, 2);
  wr_B(0);  // compiler auto-waits for xv loads (leaves the 3 DMA groups in flight)
  asm volatile("s_waitcnt lgkmcnt(0)" ::: "memory");
  __builtin_amdgcn_sched_barrier(0);
  __builtin_amdgcn_s_barrier();  // publish Bsm(0)

  int pb = 0;  // global phase base = icb*9
  for (int icb = 0; icb < 15; ++icb) {
#pragma unroll
    for (int t = 0; t < 9; ++t) {
      // counted arrival wait for tap t's own DMA (issued 3 taps ago).
      // t>=6: 16 xv loads (issued at tap 5) sit between DMA groups -> +16.
      if (t < 6) VMWAIT(4); else VMWAIT(20);
      if (t + 3 <= 8) issueA(t + 3, icb, (pb + t + 3) & 3);
      else            issueA(t - 6, icb + 1, (pb + t + 3) & 3);
      if (t == 5) ld_x(icb + 1);  // T14: issue next B x-loads under taps 5-8
      do_tap(t, (pb + t) & 3);
    }
    // ---- B restage boundary: only 2 barriers per icb ----
    __builtin_amdgcn_s_barrier();   // all waves done reading Bsm(icb)
    __builtin_amdgcn_sched_barrier(0);
    wr_B(icb + 1);                  // waits xv loads only (3 DMA groups stay in flight)
    asm volatile("s_waitcnt lgkmcnt(0)" ::: "memory");
    __builtin_amdgcn_sched_barrier(0);
    __builtin_amdgcn_s_barrier();   // publish Bsm(icb+1)
    pb += 9;
  }
  // ---- last icb = 15: drain ladder ----
#pragma unroll
  for (int t = 0; t < 9; ++t) {
    if (t < 6) {
      VMWAIT(4);
      issueA(t + 3, 15, (pb + t + 3) & 3);
    } else if (t == 6) {
      VMWAIT(4);
    } else if (t == 7) {
      VMWAIT(2);
    } else {
      VMWAIT(0);
    }
    do_tap(t, (pb + t) & 3);
  }

  // epilogue: scale by conv_scale*demod[b][oc], coalesced stores
  const float* fsb = fscale + b * OC;
#pragma unroll
  for (int i = 0; i < 2; ++i) {
#pragma unroll
    for (int rr = 0; rr < 4; ++rr) {
      const int oc = mblk * 128 + wave * 32 + i * 16 + lk * 4 + rr;
      const float sc = fsb[oc];
#pragma unroll
      for (int j = 0; j < 8; ++j) {
        out[((size_t)(b * OC + oc)) * HW + (h0 + (j >> 2)) * WW + (j & 3) * 16 + lrow] =
            acc[i][j][rr] * sc;
      }
    }
  }
}

// ---------------- launch --------------------------------------------------------
extern "C" void kernel_launch(void* const* d_in, const int* in_sizes, int n_in,
                              void* d_out, int out_size, void* d_ws, size_t ws_size,
                              hipStream_t stream) {
  const float* input = (const float*)d_in[0];       // [16,512,64,64]
  const float* style = (const float*)d_in[1];       // [16,512]
  const float* weight = (const float*)d_in[2];      // [1,512,512,3,3]
  const float* mod_weight = (const float*)d_in[3];  // [512,512]
  const float* mod_bias = (const float*)d_in[4];    // [512]
  float* out = (float*)d_out;

  char* ws = (char*)d_ws;
  constexpr size_t WPACK_B = (size_t)9 * OC * IC * 2;   // 4,718,592
  constexpr size_t W2SUM_B = (size_t)OC * IC * 4;       // 1,048,576
  constexpr size_t S_B = (size_t)BB * IC * 4;           // 32,768
  unsigned short* wpack = (unsigned short*)ws;
  float* w2sum = (float*)(ws + WPACK_B);
  float* s = (float*)(ws + WPACK_B + W2SUM_B);
  float* fscale = (float*)(ws + WPACK_B + W2SUM_B + S_B);

  k_style<<<BB, 256, 0, stream>>>(style, mod_weight, mod_bias, s);
  k_pack<<<OC, 256, 0, stream>>>(weight, wpack, w2sum);
  k_demod<<<BB, 256, 0, stream>>>(s, w2sum, fscale);
  k_conv<<<2048, 256, 0, stream>>>(input, wpack, s, fscale, out);
}